// Round 12
// baseline (259.641 us; speedup 1.0000x reference)
//
#include <hip/hip_runtime.h>

typedef unsigned int uint;
typedef unsigned short ushort;

#define B_  2
#define NA  2048
#define NN  48
#define G_  50
#define F_  128
#define NK  49   // Nn + 1 (self)
#define NROW (B_ * NA * NN)   // 196608 flat filter rows
#define NAT  (B_ * NA)        // 4096 atoms

typedef short short8 __attribute__((ext_vector_type(8)));
typedef float floatx4 __attribute__((ext_vector_type(4)));

__device__ __forceinline__ float ssp(float z) {  // softplus(z)-ln2: fast v_exp/v_log
  return fmaxf(z, 0.f) + __logf(1.f + __expf(-fabsf(z))) - 0.69314718055994531f;
}
__device__ __forceinline__ ushort f2bf(float x) {  // RNE
  union { float f; uint u; } v; v.f = x;
  uint u = v.u;
  u += 0x7fffu + ((u >> 16) & 1u);
  return (ushort)(u >> 16);
}
__device__ __forceinline__ uint pk2bf(float x, float y) {
  return (uint)f2bf(x) | ((uint)f2bf(y) << 16);
}

// =====================================================================
// P: weight prep -> transposed bf16 [n][k] tables (MFMA B-fragments)
//    for filter (Wf1,Wf2), V and O paths. Q/K stay f32.
// =====================================================================
extern "C" __global__ __launch_bounds__(256)
void prep_kernel(const float* __restrict__ Wf1, const float* __restrict__ Wf2,
                 const float* __restrict__ Wv, const float* __restrict__ Wo,
                 ushort* __restrict__ Wf1t, ushort* __restrict__ Wf2t,
                 ushort* __restrict__ Wvt, ushort* __restrict__ Wot)
{
  int gid = blockIdx.x * 256 + threadIdx.x;   // 24576 threads
  if (gid < 8192) {   // Wf1t [128][64], K padded 50->64
    int n = gid >> 6, k = gid & 63;
    Wf1t[gid] = f2bf((k < G_) ? Wf1[(size_t)k * F_ + n] : 0.f);
  }
  for (int idx = gid; idx < 3 * 16384; idx += 24576) {
    int m = idx >> 14, e = idx & 16383;
    int n = e >> 7, k = e & 127;
    const float* src = (m == 0) ? Wf2 : (m == 1) ? Wv : Wo;
    ushort* dst = (m == 0) ? Wf2t : (m == 1) ? Wvt : Wot;
    dst[e] = f2bf(src[(size_t)k * F_ + n]);
  }
}

// =====================================================================
// K0+K1 MERGED (R11-verified, VERBATIM): qv (blocks 0..511) + filter
//   (blocks 512..2047). 97 us measured; counters stable.
// =====================================================================
struct __align__(16) SmemM {
  union {
    struct {
      union {
        ushort ft[128 * 72];    // filter staging
        ushort h1[128 * 136];   // filter layer1 out
      } u;
      float C[128];
    } f;                        // 35328 B
    float  xs[32 * 128];        // qk staging (16 KB)
    ushort xb[16 * 136];        // v staging (4.25 KB)
  };
};

extern "C" __global__ __launch_bounds__(256, 4)
void fqv_kernel(const float* __restrict__ x,
                const float* __restrict__ Wq, const float* __restrict__ Wk,
                const ushort* __restrict__ Wvt,
                float* __restrict__ Qo, float* __restrict__ Ko,
                float* __restrict__ Vo,
                const float* __restrict__ fij, const float* __restrict__ r_ij,
                const ushort* __restrict__ Wf1t, const float* __restrict__ bf1,
                const ushort* __restrict__ Wf2t, const float* __restrict__ bf2p,
                float* __restrict__ out_W)
{
  __shared__ SmemM sm;
  const int t = threadIdx.x;
  const int bid = blockIdx.x;

  if (bid < 256) {
    // ---------------- qk part (verbatim, grid remap) ----------------
    const int part = bid;                  // was dim3(128, 2)
    const int f = t & 127, h = t >> 7;
    const size_t Rb = (size_t)(part & 127) * 32;
    const int yb = part >> 7;
    const float* W = yb ? Wk : Wq;
    float* O = yb ? Ko : Qo;

    {
      const float4* src = (const float4*)(x + Rb * F_);
      float4* dst = (float4*)sm.xs;
      #pragma unroll
      for (int k = 0; k < 4; ++k) dst[t + 256 * k] = src[t + 256 * k];
    }
    __syncthreads();

    float acc[16];
    #pragma unroll
    for (int j = 0; j < 16; ++j) acc[j] = 0.f;
    #pragma unroll
    for (int kc = 0; kc < 4; ++kc) {
      float wr[32];
      #pragma unroll
      for (int kk = 0; kk < 32; ++kk) wr[kk] = W[(size_t)(kc * 32 + kk) * F_ + f];
      #pragma unroll
      for (int j = 0; j < 16; ++j) {
        const float4* xr = (const float4*)&sm.xs[(h * 16 + j) * 128 + kc * 32];
        #pragma unroll
        for (int qq = 0; qq < 8; ++qq) {   // wave-uniform b128 broadcasts
          float4 v = xr[qq];
          acc[j] += v.x * wr[qq * 4] + v.y * wr[qq * 4 + 1]
                  + v.z * wr[qq * 4 + 2] + v.w * wr[qq * 4 + 3];
        }
      }
    }
    #pragma unroll
    for (int j = 0; j < 16; ++j)
      O[(Rb + h * 16 + j) * F_ + f] = acc[j];

  } else if (bid < 512) {
    // ---------------- v part (verbatim, grid remap) ----------------
    const int vb = bid - 256;
    const int lane = t & 63, w = t >> 6;
    const int c16 = lane & 15, q = lane >> 4;
    const size_t Rb = (size_t)vb * 16;

    {
      int row = t >> 4, col = (t & 15) * 8;
      float4 v0 = *(const float4*)(x + (Rb + row) * F_ + col);
      float4 v1 = *(const float4*)(x + (Rb + row) * F_ + col + 4);
      uint4 pk = { pk2bf(v0.x, v0.y), pk2bf(v0.z, v0.w),
                   pk2bf(v1.x, v1.y), pk2bf(v1.z, v1.w) };
      *(uint4*)((char*)sm.xb + row * 272 + col * 2) = pk;
    }
    __syncthreads();

    short8 bx[4];   // activation rows (B operand after swap)
    const char* ap = (const char*)sm.xb + c16 * 272 + q * 16;
    #pragma unroll
    for (int s = 0; s < 4; ++s) bx[s] = *(const short8*)(ap + s * 64);

    #pragma unroll
    for (int u = 0; u < 2; ++u) {
      int ntile = w * 2 + u;
      const char* bb = (const char*)Wvt + (ntile * 16 + c16) * 256 + q * 16;
      floatx4 acc = {0.f, 0.f, 0.f, 0.f};
      #pragma unroll
      for (int s = 0; s < 4; ++s) {
        short8 wf = *(const short8*)(bb + s * 64);
        acc = __builtin_amdgcn_mfma_f32_16x16x32_bf16(wf, bx[s], acc, 0, 0, 0);
      }
      // D: row = c16, n = ntile*16 + q*4 + r  -> contiguous float4
      *(floatx4*)(Vo + (Rb + c16) * F_ + ntile * 16 + q * 4) = acc;
    }

  } else {
    // ---------------- filter part (R4-verified body verbatim) ----------------
    const int lane = t & 63, w = t >> 6;
    const int c16 = lane & 15, q = lane >> 4;
    const int m0 = w * 32;                 // wave's first row (2 m-tiles of 16)
    const size_t Rb = (size_t)(bid - 512) * 128;

    // ---- stage f_ij -> bf16 LDS [128][72] as 2*f-1 ----
    #pragma unroll
    for (int it = 0; it < 16; ++it) {
      int idx = t + it * 256;              // 4096 = 128 rows * 32 uint slots
      int row = idx >> 5, kp = idx & 31;
      uint pk = 0;
      if (kp < 25) {
        float2 v = *(const float2*)(fij + (Rb + row) * G_ + 2 * kp);
        pk = pk2bf(2.f * v.x - 1.f, 2.f * v.y - 1.f);
      }
      ((uint*)sm.f.u.ft)[row * 36 + kp] = pk;
    }
    if (t < 128) {
      float r = r_ij[Rb + t];
      sm.f.C[t] = (r < 5.0f) ? 0.5f * (cosf(0.62831853071795864769f * r) + 1.0f) : 0.0f;
    }
    __syncthreads();

    // ---- preload layer1 A-fragments for own 32 rows (16 VGPR) ----
    short8 a1[2][2];
    #pragma unroll
    for (int mt = 0; mt < 2; ++mt) {
      const char* ap = (const char*)sm.f.u.ft + (m0 + mt * 16 + c16) * 144 + q * 16;
      a1[mt][0] = *(const short8*)(ap);
      a1[mt][1] = *(const short8*)(ap + 64);
    }
    __syncthreads();   // all waves done with ft; LDS region becomes h1

    // ---- preload ALL layer1 B-fragments (whole Wf1t, 64 VGPR) ----
    short8 b1[8][2];
    #pragma unroll
    for (int nt = 0; nt < 8; ++nt) {
      const char* bb = (const char*)Wf1t + (nt * 16 + c16) * 128 + q * 16;
      b1[nt][0] = *(const short8*)(bb);
      b1[nt][1] = *(const short8*)(bb + 64);
    }

    // ---- layer1: M=32 N=128 K=64, ssp -> h1 (own rows; no barrier) ----
    #pragma unroll
    for (int nt = 0; nt < 8; ++nt) {
      int n = nt * 16 + c16;
      float bias = bf1[n];
      #pragma unroll
      for (int mt = 0; mt < 2; ++mt) {
        floatx4 acc = {0.f, 0.f, 0.f, 0.f};
        acc = __builtin_amdgcn_mfma_f32_16x16x32_bf16(a1[mt][0], b1[nt][0], acc, 0, 0, 0);
        acc = __builtin_amdgcn_mfma_f32_16x16x32_bf16(a1[mt][1], b1[nt][1], acc, 0, 0, 0);
        #pragma unroll
        for (int r = 0; r < 4; ++r) {
          int row = m0 + mt * 16 + q * 4 + r;
          sm.f.u.h1[row * 136 + n] = f2bf(ssp(acc[r] + bias));
        }
      }
    }

    // ---- layer2 A-fragments from own h1 rows (32 VGPR) ----
    short8 a2[2][4];
    #pragma unroll
    for (int mt = 0; mt < 2; ++mt) {
      const char* ap = (const char*)sm.f.u.h1 + (m0 + mt * 16 + c16) * 272 + q * 16;
      #pragma unroll
      for (int s = 0; s < 4; ++s) a2[mt][s] = *(const short8*)(ap + s * 64);
    }

    // ---- layer2: M=32 N=128 K=128, B in 2 register groups of 16 frags ----
    #pragma unroll
    for (int g = 0; g < 2; ++g) {
      short8 b2[4][4];
      #pragma unroll
      for (int j = 0; j < 4; ++j) {
        int n = (g * 4 + j) * 16 + c16;
        const char* bb = (const char*)Wf2t + n * 256 + q * 16;
        #pragma unroll
        for (int s = 0; s < 4; ++s) b2[j][s] = *(const short8*)(bb + s * 64);
      }
      #pragma unroll
      for (int j = 0; j < 4; ++j) {
        int n = (g * 4 + j) * 16 + c16;
        float bias = bf2p[n];
        #pragma unroll
        for (int mt = 0; mt < 2; ++mt) {
          floatx4 acc = {0.f, 0.f, 0.f, 0.f};
          #pragma unroll
          for (int s = 0; s < 4; ++s)
            acc = __builtin_amdgcn_mfma_f32_16x16x32_bf16(a2[mt][s], b2[j][s], acc, 0, 0, 0);
          #pragma unroll
          for (int r = 0; r < 4; ++r) {
            int row = m0 + mt * 16 + q * 4 + r;
            out_W[(Rb + row) * F_ + n] = (acc[r] + bias) * sm.f.C[row];
          }
        }
      }
    }
  }
}

// =====================================================================
// K2+K3 MERGED: attention (R6-verified wave body VERBATIM; 16 waves =
//   16 atoms per 1024-thread block, matching out's 16-atom tile) + out
//   projection (R2-verified compute body VERBATIM, threads t<256).
//   Each attn wave's final acc (float2 at f=lane*2) is exactly one
//   bf16-pair of the out staging buffer -> written directly as
//   pk2bf(acc) into xb; one barrier; out MFMA reads xb as before.
//   Deletes the out launch + gap, out's staging pass, and the global
//   m_pre roundtrip entirely.
// =====================================================================
extern "C" __global__ __launch_bounds__(1024, 2)
void attn_out_kernel(const float* __restrict__ Q, const float* __restrict__ K,
                     const float* __restrict__ V, const float* __restrict__ Wg,
                     const int* __restrict__ nbr, const int* __restrict__ pmask,
                     const ushort* __restrict__ Wot, const float* __restrict__ bo,
                     float* __restrict__ out_m)
{
  __shared__ __align__(16) ushort xb[16 * 136];
  const int t = threadIdx.x;
  const int lane = t & 63, w = t >> 6;    // w = 0..15: one atom per wave
  const int a = blockIdx.x * 16 + w;
  const int b = a >> 11, i = a & 2047;
  const size_t base_nn = (size_t)a * NN;

  // ---------------- attn phase (R6 wave body verbatim) ----------------
  int nbrv = (lane < NN) ? nbr[base_nn + lane] : 0;
  int pmv  = (lane < NN) ? pmask[base_nn + lane] : 1;

  float2 q2 = *(const float2*)(Q + (size_t)a * F_ + lane * 2);

  float s_lane = -1e30f;
  #pragma unroll
  for (int n = 0; n < NK; ++n) {
    int src = (n == 0) ? i : __shfl(nbrv, (n > 0) ? n - 1 : 0);
    float2 k2 = *(const float2*)(K + ((size_t)b * NA + src) * F_ + lane * 2);
    float p = q2.x * k2.x + q2.y * k2.y;
    #pragma unroll
    for (int o = 32; o; o >>= 1) p += __shfl_xor(p, o);
    p *= 0.08838834764831845f;
    if (n > 0 && __shfl(pmv, n - 1) == 0) p = -1e9f;
    if (lane == n) s_lane = p;
  }

  float mx = s_lane;
  #pragma unroll
  for (int o = 32; o; o >>= 1) mx = fmaxf(mx, __shfl_xor(mx, o));
  float ev = (lane < NK) ? __expf(s_lane - mx) : 0.f;
  float sum = ev;
  #pragma unroll
  for (int o = 32; o; o >>= 1) sum += __shfl_xor(sum, o);
  float attn_l = ev / sum;

  float2 acc = {0.f, 0.f};
  #pragma unroll 8
  for (int n = 0; n < NK; ++n) {
    float an = __shfl(attn_l, n);
    int src = (n == 0) ? i : __shfl(nbrv, (n > 0) ? n - 1 : 0);
    float2 v2 = *(const float2*)(V + ((size_t)b * NA + src) * F_ + lane * 2);
    float2 w2 = {1.f, 1.f};
    if (n > 0) w2 = *(const float2*)(Wg + (base_nn + n - 1) * F_ + lane * 2);
    acc.x += an * w2.x * v2.x;
    acc.y += an * w2.y * v2.y;
  }
  // m_pre bf16-pair straight into out staging (row = atom w, pair = lane)
  ((uint*)((char*)xb + w * 272))[lane] = pk2bf(acc.x, acc.y);

  __syncthreads();

  // ---------------- out phase (R2 compute body verbatim, t<256) ----------------
  if (t < 256) {
    const int c16 = lane & 15, q = lane >> 4;   // w = t>>6 in 0..3 as original
    const size_t Rb = (size_t)blockIdx.x * 16;

    short8 bx[4];
    const char* ap = (const char*)xb + c16 * 272 + q * 16;
    #pragma unroll
    for (int s = 0; s < 4; ++s) bx[s] = *(const short8*)(ap + s * 64);

    #pragma unroll
    for (int u = 0; u < 2; ++u) {
      int ntile = w * 2 + u;
      const char* bb = (const char*)Wot + (ntile * 16 + c16) * 256 + q * 16;
      floatx4 acc2 = {0.f, 0.f, 0.f, 0.f};
      #pragma unroll
      for (int s = 0; s < 4; ++s) {
        short8 wf = *(const short8*)(bb + s * 64);
        acc2 = __builtin_amdgcn_mfma_f32_16x16x32_bf16(wf, bx[s], acc2, 0, 0, 0);
      }
      int n0 = ntile * 16 + q * 4;
      float4 bv = *(const float4*)&bo[n0];
      floatx4 outv;
      outv[0] = ssp(acc2[0] + bv.x);
      outv[1] = ssp(acc2[1] + bv.y);
      outv[2] = ssp(acc2[2] + bv.z);
      outv[3] = ssp(acc2[3] + bv.w);
      *(floatx4*)(out_m + (Rb + c16) * F_ + n0) = outv;
    }
  }
}

extern "C" void kernel_launch(void* const* d_in, const int* in_sizes, int n_in,
                              void* d_out, int out_size, void* d_ws, size_t ws_size,
                              hipStream_t stream) {
  // inputs: 0=e(unused) 1=x 2=t(unused) 3=r_ij 4=neighbors 5=pairwise_mask 6=f_ij
  //         7=Wf1 8=bf1 9=Wf2 10=bf2 11=Wq 12=Wk 13=Wv 14=Wo 15=bo
  const float* x   = (const float*)d_in[1];
  const float* r   = (const float*)d_in[3];
  const int*  nbr  = (const int*)d_in[4];
  const int*  pmk  = (const int*)d_in[5];
  const float* fij = (const float*)d_in[6];
  const float* Wf1 = (const float*)d_in[7];
  const float* bf1 = (const float*)d_in[8];
  const float* Wf2 = (const float*)d_in[9];
  const float* bf2p= (const float*)d_in[10];
  const float* Wq  = (const float*)d_in[11];
  const float* Wk  = (const float*)d_in[12];
  const float* Wv  = (const float*)d_in[13];
  const float* Wo  = (const float*)d_in[14];
  const float* bo  = (const float*)d_in[15];
  float* out_m = (float*)d_out;                       // [B,Na,F]
  float* out_W = out_m + (size_t)NAT * F_;            // [B,Na,Nn,F]

  // ws: Q|K|V|m_pre(now unused) (4x2MB f32) | Wf1t | Wf2t | Wvt | Wot (bf16)
  float* Qs = (float*)d_ws;
  float* Ks = Qs + (size_t)NAT * F_;
  float* Vs = Ks + (size_t)NAT * F_;
  float* Ms = Vs + (size_t)NAT * F_;
  ushort* Wf1t = (ushort*)(Ms + (size_t)NAT * F_);
  ushort* Wf2t = Wf1t + 128 * 64;
  ushort* Wvt  = Wf2t + 128 * 128;
  ushort* Wot  = Wvt  + 128 * 128;

  hipLaunchKernelGGL(prep_kernel, dim3(96), dim3(256), 0, stream,
                     Wf1, Wf2, Wv, Wo, Wf1t, Wf2t, Wvt, Wot);
  hipLaunchKernelGGL(fqv_kernel, dim3(512 + NROW / 128), dim3(256), 0, stream,
                     x, Wq, Wk, Wvt, Qs, Ks, Vs,
                     fij, r, Wf1t, bf1, Wf2t, bf2p, out_W);
  hipLaunchKernelGGL(attn_out_kernel, dim3(NAT / 16), dim3(1024), 0, stream,
                     Qs, Ks, Vs, out_W, nbr, pmk, Wot, bo, out_m);
}

// Round 13
// 245.814 us; speedup vs baseline: 1.0562x; 1.0562x over previous
//
#include <hip/hip_runtime.h>

typedef unsigned int uint;
typedef unsigned short ushort;

#define B_  2
#define NA  2048
#define NN  48
#define G_  50
#define F_  128
#define NK  49   // Nn + 1 (self)
#define NROW (B_ * NA * NN)   // 196608 flat filter rows
#define NAT  (B_ * NA)        // 4096 atoms

typedef short short8 __attribute__((ext_vector_type(8)));
typedef float floatx4 __attribute__((ext_vector_type(4)));

__device__ __forceinline__ float ssp(float z) {  // softplus(z)-ln2: fast v_exp/v_log
  return fmaxf(z, 0.f) + __logf(1.f + __expf(-fabsf(z))) - 0.69314718055994531f;
}
__device__ __forceinline__ ushort f2bf(float x) {  // RNE
  union { float f; uint u; } v; v.f = x;
  uint u = v.u;
  u += 0x7fffu + ((u >> 16) & 1u);
  return (ushort)(u >> 16);
}
__device__ __forceinline__ uint pk2bf(float x, float y) {
  return (uint)f2bf(x) | ((uint)f2bf(y) << 16);
}

// =====================================================================
// P: weight prep -> transposed bf16 [n][k] tables (MFMA B-fragments)
//    for filter (Wf1,Wf2), V and O paths. Q/K stay f32.
// =====================================================================
extern "C" __global__ __launch_bounds__(256)
void prep_kernel(const float* __restrict__ Wf1, const float* __restrict__ Wf2,
                 const float* __restrict__ Wv, const float* __restrict__ Wo,
                 ushort* __restrict__ Wf1t, ushort* __restrict__ Wf2t,
                 ushort* __restrict__ Wvt, ushort* __restrict__ Wot)
{
  int gid = blockIdx.x * 256 + threadIdx.x;   // 24576 threads
  if (gid < 8192) {   // Wf1t [128][64], K padded 50->64
    int n = gid >> 6, k = gid & 63;
    Wf1t[gid] = f2bf((k < G_) ? Wf1[(size_t)k * F_ + n] : 0.f);
  }
  for (int idx = gid; idx < 3 * 16384; idx += 24576) {
    int m = idx >> 14, e = idx & 16383;
    int n = e >> 7, k = e & 127;
    const float* src = (m == 0) ? Wf2 : (m == 1) ? Wv : Wo;
    ushort* dst = (m == 0) ? Wf2t : (m == 1) ? Wvt : Wot;
    dst[e] = f2bf(src[(size_t)k * F_ + n]);
  }
}

// =====================================================================
// K0+K1 MERGED — LPT-reordered: filter (the long-pole, latency-bound
//   blocks) now dispatches FIRST (bids 0..1535) so it starts on every
//   CU immediately; the 512 short qv blocks (qk: 1536..1791, v:
//   1792..2047) backfill idle wave slots while the filter wavefront
//   drains. R11 order (qv first) serialized qv ahead of the makespan
//   (fqv = 97 = filter 81 + ~16). Bodies byte-identical to R11/R12.
// =====================================================================
struct __align__(16) SmemM {
  union {
    struct {
      union {
        ushort ft[128 * 72];    // filter staging
        ushort h1[128 * 136];   // filter layer1 out
      } u;
      float C[128];
    } f;                        // 35328 B
    float  xs[32 * 128];        // qk staging (16 KB)
    ushort xb[16 * 136];        // v staging (4.25 KB)
  };
};

extern "C" __global__ __launch_bounds__(256, 4)
void fqv_kernel(const float* __restrict__ x,
                const float* __restrict__ Wq, const float* __restrict__ Wk,
                const ushort* __restrict__ Wvt,
                float* __restrict__ Qo, float* __restrict__ Ko,
                float* __restrict__ Vo,
                const float* __restrict__ fij, const float* __restrict__ r_ij,
                const ushort* __restrict__ Wf1t, const float* __restrict__ bf1,
                const ushort* __restrict__ Wf2t, const float* __restrict__ bf2p,
                float* __restrict__ out_W)
{
  __shared__ SmemM sm;
  const int t = threadIdx.x;
  const int bid = blockIdx.x;

  if (bid < 1536) {
    // ---------------- filter part (R4-verified body verbatim) ----------------
    const int lane = t & 63, w = t >> 6;
    const int c16 = lane & 15, q = lane >> 4;
    const int m0 = w * 32;                 // wave's first row (2 m-tiles of 16)
    const size_t Rb = (size_t)bid * 128;

    // ---- stage f_ij -> bf16 LDS [128][72] as 2*f-1 ----
    #pragma unroll
    for (int it = 0; it < 16; ++it) {
      int idx = t + it * 256;              // 4096 = 128 rows * 32 uint slots
      int row = idx >> 5, kp = idx & 31;
      uint pk = 0;
      if (kp < 25) {
        float2 v = *(const float2*)(fij + (Rb + row) * G_ + 2 * kp);
        pk = pk2bf(2.f * v.x - 1.f, 2.f * v.y - 1.f);
      }
      ((uint*)sm.f.u.ft)[row * 36 + kp] = pk;
    }
    if (t < 128) {
      float r = r_ij[Rb + t];
      sm.f.C[t] = (r < 5.0f) ? 0.5f * (cosf(0.62831853071795864769f * r) + 1.0f) : 0.0f;
    }
    __syncthreads();

    // ---- preload layer1 A-fragments for own 32 rows (16 VGPR) ----
    short8 a1[2][2];
    #pragma unroll
    for (int mt = 0; mt < 2; ++mt) {
      const char* ap = (const char*)sm.f.u.ft + (m0 + mt * 16 + c16) * 144 + q * 16;
      a1[mt][0] = *(const short8*)(ap);
      a1[mt][1] = *(const short8*)(ap + 64);
    }
    __syncthreads();   // all waves done with ft; LDS region becomes h1

    // ---- preload ALL layer1 B-fragments (whole Wf1t, 64 VGPR) ----
    short8 b1[8][2];
    #pragma unroll
    for (int nt = 0; nt < 8; ++nt) {
      const char* bb = (const char*)Wf1t + (nt * 16 + c16) * 128 + q * 16;
      b1[nt][0] = *(const short8*)(bb);
      b1[nt][1] = *(const short8*)(bb + 64);
    }

    // ---- layer1: M=32 N=128 K=64, ssp -> h1 (own rows; no barrier) ----
    #pragma unroll
    for (int nt = 0; nt < 8; ++nt) {
      int n = nt * 16 + c16;
      float bias = bf1[n];
      #pragma unroll
      for (int mt = 0; mt < 2; ++mt) {
        floatx4 acc = {0.f, 0.f, 0.f, 0.f};
        acc = __builtin_amdgcn_mfma_f32_16x16x32_bf16(a1[mt][0], b1[nt][0], acc, 0, 0, 0);
        acc = __builtin_amdgcn_mfma_f32_16x16x32_bf16(a1[mt][1], b1[nt][1], acc, 0, 0, 0);
        #pragma unroll
        for (int r = 0; r < 4; ++r) {
          int row = m0 + mt * 16 + q * 4 + r;
          sm.f.u.h1[row * 136 + n] = f2bf(ssp(acc[r] + bias));
        }
      }
    }

    // ---- layer2 A-fragments from own h1 rows (32 VGPR) ----
    short8 a2[2][4];
    #pragma unroll
    for (int mt = 0; mt < 2; ++mt) {
      const char* ap = (const char*)sm.f.u.h1 + (m0 + mt * 16 + c16) * 272 + q * 16;
      #pragma unroll
      for (int s = 0; s < 4; ++s) a2[mt][s] = *(const short8*)(ap + s * 64);
    }

    // ---- layer2: M=32 N=128 K=128, B in 2 register groups of 16 frags ----
    #pragma unroll
    for (int g = 0; g < 2; ++g) {
      short8 b2[4][4];
      #pragma unroll
      for (int j = 0; j < 4; ++j) {
        int n = (g * 4 + j) * 16 + c16;
        const char* bb = (const char*)Wf2t + n * 256 + q * 16;
        #pragma unroll
        for (int s = 0; s < 4; ++s) b2[j][s] = *(const short8*)(bb + s * 64);
      }
      #pragma unroll
      for (int j = 0; j < 4; ++j) {
        int n = (g * 4 + j) * 16 + c16;
        float bias = bf2p[n];
        #pragma unroll
        for (int mt = 0; mt < 2; ++mt) {
          floatx4 acc = {0.f, 0.f, 0.f, 0.f};
          #pragma unroll
          for (int s = 0; s < 4; ++s)
            acc = __builtin_amdgcn_mfma_f32_16x16x32_bf16(a2[mt][s], b2[j][s], acc, 0, 0, 0);
          #pragma unroll
          for (int r = 0; r < 4; ++r) {
            int row = m0 + mt * 16 + q * 4 + r;
            out_W[(Rb + row) * F_ + n] = (acc[r] + bias) * sm.f.C[row];
          }
        }
      }
    }

  } else if (bid < 1792) {
    // ---------------- qk part (verbatim, grid remap) ----------------
    const int part = bid - 1536;           // was dim3(128, 2)
    const int f = t & 127, h = t >> 7;
    const size_t Rb = (size_t)(part & 127) * 32;
    const int yb = part >> 7;
    const float* W = yb ? Wk : Wq;
    float* O = yb ? Ko : Qo;

    {
      const float4* src = (const float4*)(x + Rb * F_);
      float4* dst = (float4*)sm.xs;
      #pragma unroll
      for (int k = 0; k < 4; ++k) dst[t + 256 * k] = src[t + 256 * k];
    }
    __syncthreads();

    float acc[16];
    #pragma unroll
    for (int j = 0; j < 16; ++j) acc[j] = 0.f;
    #pragma unroll
    for (int kc = 0; kc < 4; ++kc) {
      float wr[32];
      #pragma unroll
      for (int kk = 0; kk < 32; ++kk) wr[kk] = W[(size_t)(kc * 32 + kk) * F_ + f];
      #pragma unroll
      for (int j = 0; j < 16; ++j) {
        const float4* xr = (const float4*)&sm.xs[(h * 16 + j) * 128 + kc * 32];
        #pragma unroll
        for (int qq = 0; qq < 8; ++qq) {   // wave-uniform b128 broadcasts
          float4 v = xr[qq];
          acc[j] += v.x * wr[qq * 4] + v.y * wr[qq * 4 + 1]
                  + v.z * wr[qq * 4 + 2] + v.w * wr[qq * 4 + 3];
        }
      }
    }
    #pragma unroll
    for (int j = 0; j < 16; ++j)
      O[(Rb + h * 16 + j) * F_ + f] = acc[j];

  } else {
    // ---------------- v part (verbatim, grid remap) ----------------
    const int vb = bid - 1792;
    const int lane = t & 63, w = t >> 6;
    const int c16 = lane & 15, q = lane >> 4;
    const size_t Rb = (size_t)vb * 16;

    {
      int row = t >> 4, col = (t & 15) * 8;
      float4 v0 = *(const float4*)(x + (Rb + row) * F_ + col);
      float4 v1 = *(const float4*)(x + (Rb + row) * F_ + col + 4);
      uint4 pk = { pk2bf(v0.x, v0.y), pk2bf(v0.z, v0.w),
                   pk2bf(v1.x, v1.y), pk2bf(v1.z, v1.w) };
      *(uint4*)((char*)sm.xb + row * 272 + col * 2) = pk;
    }
    __syncthreads();

    short8 bx[4];   // activation rows (B operand after swap)
    const char* ap = (const char*)sm.xb + c16 * 272 + q * 16;
    #pragma unroll
    for (int s = 0; s < 4; ++s) bx[s] = *(const short8*)(ap + s * 64);

    #pragma unroll
    for (int u = 0; u < 2; ++u) {
      int ntile = w * 2 + u;
      const char* bb = (const char*)Wvt + (ntile * 16 + c16) * 256 + q * 16;
      floatx4 acc = {0.f, 0.f, 0.f, 0.f};
      #pragma unroll
      for (int s = 0; s < 4; ++s) {
        short8 wf = *(const short8*)(bb + s * 64);
        acc = __builtin_amdgcn_mfma_f32_16x16x32_bf16(wf, bx[s], acc, 0, 0, 0);
      }
      // D: row = c16, n = ntile*16 + q*4 + r  -> contiguous float4
      *(floatx4*)(Vo + (Rb + c16) * F_ + ntile * 16 + q * 4) = acc;
    }
  }
}

// =====================================================================
// K2+K3 MERGED (R12-verified, VERBATIM): attention (R6 wave body; 16
//   waves = 16 atoms per 1024-thread block) + out projection (R2 body,
//   t<256) with m_pre passed through LDS. Saved ~21 us vs separate
//   launches (R12 ledger).
// =====================================================================
extern "C" __global__ __launch_bounds__(1024, 2)
void attn_out_kernel(const float* __restrict__ Q, const float* __restrict__ K,
                     const float* __restrict__ V, const float* __restrict__ Wg,
                     const int* __restrict__ nbr, const int* __restrict__ pmask,
                     const ushort* __restrict__ Wot, const float* __restrict__ bo,
                     float* __restrict__ out_m)
{
  __shared__ __align__(16) ushort xb[16 * 136];
  const int t = threadIdx.x;
  const int lane = t & 63, w = t >> 6;    // w = 0..15: one atom per wave
  const int a = blockIdx.x * 16 + w;
  const int b = a >> 11, i = a & 2047;
  const size_t base_nn = (size_t)a * NN;

  // ---------------- attn phase (R6 wave body verbatim) ----------------
  int nbrv = (lane < NN) ? nbr[base_nn + lane] : 0;
  int pmv  = (lane < NN) ? pmask[base_nn + lane] : 1;

  float2 q2 = *(const float2*)(Q + (size_t)a * F_ + lane * 2);

  float s_lane = -1e30f;
  #pragma unroll
  for (int n = 0; n < NK; ++n) {
    int src = (n == 0) ? i : __shfl(nbrv, (n > 0) ? n - 1 : 0);
    float2 k2 = *(const float2*)(K + ((size_t)b * NA + src) * F_ + lane * 2);
    float p = q2.x * k2.x + q2.y * k2.y;
    #pragma unroll
    for (int o = 32; o; o >>= 1) p += __shfl_xor(p, o);
    p *= 0.08838834764831845f;
    if (n > 0 && __shfl(pmv, n - 1) == 0) p = -1e9f;
    if (lane == n) s_lane = p;
  }

  float mx = s_lane;
  #pragma unroll
  for (int o = 32; o; o >>= 1) mx = fmaxf(mx, __shfl_xor(mx, o));
  float ev = (lane < NK) ? __expf(s_lane - mx) : 0.f;
  float sum = ev;
  #pragma unroll
  for (int o = 32; o; o >>= 1) sum += __shfl_xor(sum, o);
  float attn_l = ev / sum;

  float2 acc = {0.f, 0.f};
  #pragma unroll 8
  for (int n = 0; n < NK; ++n) {
    float an = __shfl(attn_l, n);
    int src = (n == 0) ? i : __shfl(nbrv, (n > 0) ? n - 1 : 0);
    float2 v2 = *(const float2*)(V + ((size_t)b * NA + src) * F_ + lane * 2);
    float2 w2 = {1.f, 1.f};
    if (n > 0) w2 = *(const float2*)(Wg + (base_nn + n - 1) * F_ + lane * 2);
    acc.x += an * w2.x * v2.x;
    acc.y += an * w2.y * v2.y;
  }
  // m_pre bf16-pair straight into out staging (row = atom w, pair = lane)
  ((uint*)((char*)xb + w * 272))[lane] = pk2bf(acc.x, acc.y);

  __syncthreads();

  // ---------------- out phase (R2 compute body verbatim, t<256) ----------------
  if (t < 256) {
    const int c16 = lane & 15, q = lane >> 4;   // w = t>>6 in 0..3 as original
    const size_t Rb = (size_t)blockIdx.x * 16;

    short8 bx[4];
    const char* ap = (const char*)xb + c16 * 272 + q * 16;
    #pragma unroll
    for (int s = 0; s < 4; ++s) bx[s] = *(const short8*)(ap + s * 64);

    #pragma unroll
    for (int u = 0; u < 2; ++u) {
      int ntile = w * 2 + u;
      const char* bb = (const char*)Wot + (ntile * 16 + c16) * 256 + q * 16;
      floatx4 acc2 = {0.f, 0.f, 0.f, 0.f};
      #pragma unroll
      for (int s = 0; s < 4; ++s) {
        short8 wf = *(const short8*)(bb + s * 64);
        acc2 = __builtin_amdgcn_mfma_f32_16x16x32_bf16(wf, bx[s], acc2, 0, 0, 0);
      }
      int n0 = ntile * 16 + q * 4;
      float4 bv = *(const float4*)&bo[n0];
      floatx4 outv;
      outv[0] = ssp(acc2[0] + bv.x);
      outv[1] = ssp(acc2[1] + bv.y);
      outv[2] = ssp(acc2[2] + bv.z);
      outv[3] = ssp(acc2[3] + bv.w);
      *(floatx4*)(out_m + (Rb + c16) * F_ + n0) = outv;
    }
  }
}

extern "C" void kernel_launch(void* const* d_in, const int* in_sizes, int n_in,
                              void* d_out, int out_size, void* d_ws, size_t ws_size,
                              hipStream_t stream) {
  // inputs: 0=e(unused) 1=x 2=t(unused) 3=r_ij 4=neighbors 5=pairwise_mask 6=f_ij
  //         7=Wf1 8=bf1 9=Wf2 10=bf2 11=Wq 12=Wk 13=Wv 14=Wo 15=bo
  const float* x   = (const float*)d_in[1];
  const float* r   = (const float*)d_in[3];
  const int*  nbr  = (const int*)d_in[4];
  const int*  pmk  = (const int*)d_in[5];
  const float* fij = (const float*)d_in[6];
  const float* Wf1 = (const float*)d_in[7];
  const float* bf1 = (const float*)d_in[8];
  const float* Wf2 = (const float*)d_in[9];
  const float* bf2p= (const float*)d_in[10];
  const float* Wq  = (const float*)d_in[11];
  const float* Wk  = (const float*)d_in[12];
  const float* Wv  = (const float*)d_in[13];
  const float* Wo  = (const float*)d_in[14];
  const float* bo  = (const float*)d_in[15];
  float* out_m = (float*)d_out;                       // [B,Na,F]
  float* out_W = out_m + (size_t)NAT * F_;            // [B,Na,Nn,F]

  // ws: Q|K|V|m_pre(unused) (4x2MB f32) | Wf1t | Wf2t | Wvt | Wot (bf16)
  float* Qs = (float*)d_ws;
  float* Ks = Qs + (size_t)NAT * F_;
  float* Vs = Ks + (size_t)NAT * F_;
  float* Ms = Vs + (size_t)NAT * F_;
  ushort* Wf1t = (ushort*)(Ms + (size_t)NAT * F_);
  ushort* Wf2t = Wf1t + 128 * 64;
  ushort* Wvt  = Wf2t + 128 * 128;
  ushort* Wot  = Wvt  + 128 * 128;

  hipLaunchKernelGGL(prep_kernel, dim3(96), dim3(256), 0, stream,
                     Wf1, Wf2, Wv, Wo, Wf1t, Wf2t, Wvt, Wot);
  hipLaunchKernelGGL(fqv_kernel, dim3(512 + NROW / 128), dim3(256), 0, stream,
                     x, Wq, Wk, Wvt, Qs, Ks, Vs,
                     fij, r, Wf1t, bf1, Wf2t, bf2p, out_W);
  hipLaunchKernelGGL(attn_out_kernel, dim3(NAT / 16), dim3(1024), 0, stream,
                     Qs, Ks, Vs, out_W, nbr, pmk, Wot, bo, out_m);
}